// Round 4
// baseline (501.620 us; speedup 1.0000x reference)
//
#include <hip/hip_runtime.h>
#include <cstdint>

#define N 8192
#define FIN 256
#define FOUT 128
#define ALPHA 0.2f
#define JP 4                  // j-split
#define JSL (N / JP)          // 2048 j per block
#define TJ 64                 // j-tile
#define NTILE (JSL / TJ)      // 32 tiles
#define RB 32                 // rows per block

typedef unsigned short u16;
typedef unsigned char u8;
typedef __attribute__((ext_vector_type(8))) short short8;
typedef __attribute__((ext_vector_type(4))) float floatx4;

__device__ __forceinline__ u16 bf16_rne(float f) {
  uint32_t u = __float_as_uint(f);
  u += 0x7fff + ((u >> 16) & 1);
  return (u16)(u >> 16);
}

// ---------------------------------------------------------------------------
// Kernel 0: adj (int32, 268 MB) -> bitmask (8 MB). Pure streaming at full
// HBM BW; this is the pipeline's one unavoidable big read (~44 us floor).
// ---------------------------------------------------------------------------
__global__ __launch_bounds__(256) void k_pack(const int* __restrict__ adj,
                                              uint32_t* __restrict__ bm) {
  const int t = blockIdx.x * 256 + threadIdx.x;    // 0 .. N*N/32-1
  const int4* p = (const int4*)adj + (size_t)t * 8;
  int4 v[8];
  #pragma unroll
  for (int k = 0; k < 8; ++k) v[k] = p[k];
  uint32_t m = 0;
  #pragma unroll
  for (int k = 0; k < 8; ++k) {
    m |= (uint32_t)(v[k].x > 0) << (4 * k + 0);
    m |= (uint32_t)(v[k].y > 0) << (4 * k + 1);
    m |= (uint32_t)(v[k].z > 0) << (4 * k + 2);
    m |= (uint32_t)(v[k].w > 0) << (4 * k + 3);
  }
  bm[t] = m;
}

// ---------------------------------------------------------------------------
// Kernel 1: h = x@W (fp32); hT3 bf16 tiled [jb][nt][m*4+q][8]; src = h@a1,
// dst = h@a2.  (round-2 version, unchanged)
// ---------------------------------------------------------------------------
__global__ __launch_bounds__(256) void k_proj(const float* __restrict__ x,
                                              const float* __restrict__ W,
                                              const float* __restrict__ a,
                                              u16* __restrict__ hT3,
                                              float* __restrict__ srcv,
                                              float* __restrict__ dstv) {
  __shared__ float xs[8 * FIN];                     // 8 KB
  __shared__ float partS[4][4], partD[4][4];
  const int t = threadIdx.x;
  const int R0 = blockIdx.x * 8;

  const float4* xv = (const float4*)(x + (size_t)R0 * FIN);
  float4* xsv = (float4*)xs;
  xsv[t] = xv[t];
  xsv[t + 256] = xv[t + 256];
  __syncthreads();

  const int c  = t & 127;
  const int rg = (t >> 7) * 4;

  float acc[4] = {0.f, 0.f, 0.f, 0.f};
  float wa[4], wb[4];
  #pragma unroll
  for (int j = 0; j < 4; ++j) wa[j] = W[j * FOUT + c];
  #pragma unroll
  for (int j = 0; j < 4; ++j) wb[j] = W[(4 + j) * FOUT + c];

  for (int k4 = 0; k4 < FIN / 4; ++k4) {
    float wc[4];
    #pragma unroll
    for (int j = 0; j < 4; ++j) { wc[j] = wa[j]; wa[j] = wb[j]; }
    const int kn = (k4 + 2 < FIN / 4) ? k4 + 2 : k4;
    #pragma unroll
    for (int j = 0; j < 4; ++j) wb[j] = W[(kn * 4 + j) * FOUT + c];
    #pragma unroll
    for (int i = 0; i < 4; ++i) {
      const float4 xq = *(const float4*)&xs[(rg + i) * FIN + k4 * 4];
      acc[i] += xq.x * wc[0] + xq.y * wc[1] + xq.z * wc[2] + xq.w * wc[3];
    }
  }

  {
    const int j = R0 + rg;
    const int jb = j >> 5, q = (j >> 3) & 3, jj = j & 7;
    const int m = c & 15, nt = c >> 4;
    union { u16 u[4]; uint2 v; } pk;
    #pragma unroll
    for (int i = 0; i < 4; ++i) pk.u[i] = bf16_rne(acc[i]);
    *(uint2*)(hT3 + (size_t)(((jb * 8 + nt) * 64) + (m * 4 + q)) * 8 + jj) = pk.v;
  }

  const float a1 = a[c], a2 = a[FOUT + c];
  float s4[4], d4[4];
  #pragma unroll
  for (int i = 0; i < 4; ++i) { s4[i] = acc[i] * a1; d4[i] = acc[i] * a2; }
  #pragma unroll
  for (int off = 32; off > 0; off >>= 1) {
    #pragma unroll
    for (int i = 0; i < 4; ++i) {
      s4[i] += __shfl_down(s4[i], off);
      d4[i] += __shfl_down(d4[i], off);
    }
  }
  const int wv = t >> 6, lane = t & 63;
  if (lane == 0) {
    #pragma unroll
    for (int i = 0; i < 4; ++i) { partS[wv][i] = s4[i]; partD[wv][i] = d4[i]; }
  }
  __syncthreads();
  if (t < 16) {
    const int i = t & 3, rg2 = (t >> 2) & 1, which = t >> 3;
    if (which == 0) srcv[R0 + rg2 * 4 + i] = partS[rg2*2][i] + partS[rg2*2+1][i];
    else            dstv[R0 + rg2 * 4 + i] = partD[rg2*2][i] + partD[rg2*2+1][i];
  }
}

// ---------------------------------------------------------------------------
// Kernel 2: GAT, round-4 — BARRIER-FREE. No LDS, no s_barrier, no DMA.
// Wave w owns output cols [w*32, w*32+32) (nt' = 2w, 2w+1): B-fragments are
// disjoint per wave -> zero B duplication; read directly from L2-resident
// hT3 (512 MB total L2 traffic ~ 15 us, cut further by L1 since co-resident
// blocks walk the same tiles). Each lane computes its 4 A-frags (rh x k) in
// registers from srcv/dstv/bitmask (4x exp duplication — exp aggregate is
// only ~7 us even at 4x). 1-deep register prefetch ping-pong (static names);
// 4+ independent waves/SIMD hide L2 latency with no sync coupling at all.
// ---------------------------------------------------------------------------
__global__ __launch_bounds__(256) void k_gat(const u8* __restrict__ bmk,
                                             const u16* __restrict__ hT3,
                                             const float* __restrict__ srcv,
                                             const float* __restrict__ dstv,
                                             float* __restrict__ P,
                                             float* __restrict__ lp) {
  const int t = threadIdx.x;
  const int w = t >> 6, lane = t & 63;
  const int q = lane >> 4, m = lane & 15;
  const int bm = blockIdx.x & 255;
  const int jp = blockIdx.x >> 8;
  const int R0 = bm * RB;
  const int j0 = jp * JSL;
  const int nt0 = 2 * w, nt1 = 2 * w + 1;      // this wave's col-tiles
  const int Lq = m * 4 + q;                    // hT3 lane index

  // A-frag row scalars: rows R0+m (rh=0) and R0+16+m (rh=1)
  const float sr0 = srcv[R0 + m];
  const float sr1 = srcv[R0 + 16 + m];
  const float* dstp = dstv + j0 + q * 8;       // + T*64 (+32 for k=1)
  const u8* bmp0 = bmk + (size_t)(R0 + m) * (N >> 3) + (j0 >> 3) + q;
  const u8* bmp1 = bmp0 + (size_t)16 * (N >> 3);

  // B-frag base pointers: b<k><n> = hT3[((jb00 + k)*8 + nt_n)*512 + Lq*8];
  // per-tile advance = 2*8*512 = 8192 u16.
  const size_t jb00 = (size_t)(j0 >> 5);
  const u16* b00 = hT3 + ((jb00 + 0) * 8 + nt0) * 512 + Lq * 8;
  const u16* b01 = hT3 + ((jb00 + 0) * 8 + nt1) * 512 + Lq * 8;
  const u16* b10 = hT3 + ((jb00 + 1) * 8 + nt0) * 512 + Lq * 8;
  const u16* b11 = hT3 + ((jb00 + 1) * 8 + nt1) * 512 + Lq * 8;

  floatx4 acc[2][2];
  #pragma unroll
  for (int i = 0; i < 2; ++i)
    #pragma unroll
    for (int j = 0; j < 2; ++j) acc[i][j] = (floatx4){0.f, 0.f, 0.f, 0.f};
  float ls0 = 0.f, ls1 = 0.f;

  // A-frag (one rh, one k-half): 8 p-values for cols df[0..7], gated by mask
  auto mk_frag = [&](float srcr, const float4 dlo, const float4 dhi,
                     const u8 mk, float& ls) -> short8 {
    union { u16 u[8]; short8 s; } A_;
    const float df[8] = {dlo.x, dlo.y, dlo.z, dlo.w, dhi.x, dhi.y, dhi.z, dhi.w};
    #pragma unroll
    for (int e = 0; e < 8; ++e) {
      float v = srcr + df[e];
      v = fmaxf(v, ALPHA * v);
      const float p = ((mk >> e) & 1) ? __expf(v) : 0.f;
      ls += p;
      A_.u[e] = bf16_rne(p);
    }
    return A_.s;
  };

  // Load all tile-T inputs into named regs
  #define LOADT(T, B00, B01, B10, B11, D0, D1, D2, D3, M00, M01, M10, M11)     \
    B00 = *(const short8*)(b00 + (size_t)(T) * 8192);                          \
    B01 = *(const short8*)(b01 + (size_t)(T) * 8192);                          \
    B10 = *(const short8*)(b10 + (size_t)(T) * 8192);                          \
    B11 = *(const short8*)(b11 + (size_t)(T) * 8192);                          \
    D0 = *(const float4*)(dstp + (T) * TJ);                                    \
    D1 = *(const float4*)(dstp + (T) * TJ + 4);                                \
    D2 = *(const float4*)(dstp + (T) * TJ + 32);                               \
    D3 = *(const float4*)(dstp + (T) * TJ + 36);                               \
    M00 = bmp0[(T) * 8]; M01 = bmp0[(T) * 8 + 4];                              \
    M10 = bmp1[(T) * 8]; M11 = bmp1[(T) * 8 + 4];

  // Compute tile from named regs: 4 A-frags (rh x k), 8 MFMAs
  #define COMPT(B00, B01, B10, B11, D0, D1, D2, D3, M00, M01, M10, M11)        \
  {                                                                            \
    const short8 a00 = mk_frag(sr0, D0, D1, M00, ls0);  /* rh0, k0 */          \
    const short8 a01 = mk_frag(sr0, D2, D3, M01, ls0);  /* rh0, k1 */          \
    const short8 a10 = mk_frag(sr1, D0, D1, M10, ls1);  /* rh1, k0 */          \
    const short8 a11 = mk_frag(sr1, D2, D3, M11, ls1);  /* rh1, k1 */          \
    acc[0][0] = __builtin_amdgcn_mfma_f32_16x16x32_bf16(a00, B00, acc[0][0], 0, 0, 0); \
    acc[0][0] = __builtin_amdgcn_mfma_f32_16x16x32_bf16(a01, B10, acc[0][0], 0, 0, 0); \
    acc[0][1] = __builtin_amdgcn_mfma_f32_16x16x32_bf16(a00, B01, acc[0][1], 0, 0, 0); \
    acc[0][1] = __builtin_amdgcn_mfma_f32_16x16x32_bf16(a01, B11, acc[0][1], 0, 0, 0); \
    acc[1][0] = __builtin_amdgcn_mfma_f32_16x16x32_bf16(a10, B00, acc[1][0], 0, 0, 0); \
    acc[1][0] = __builtin_amdgcn_mfma_f32_16x16x32_bf16(a11, B10, acc[1][0], 0, 0, 0); \
    acc[1][1] = __builtin_amdgcn_mfma_f32_16x16x32_bf16(a10, B01, acc[1][1], 0, 0, 0); \
    acc[1][1] = __builtin_amdgcn_mfma_f32_16x16x32_bf16(a11, B11, acc[1][1], 0, 0, 0); \
  }

  // ping-pong register sets (all static names — rule #20)
  short8 cB00, cB01, cB10, cB11, nB00, nB01, nB10, nB11;
  float4 cD0, cD1, cD2, cD3, nD0, nD1, nD2, nD3;
  u8 cM00, cM01, cM10, cM11, nM00, nM01, nM10, nM11;

  LOADT(0, cB00, cB01, cB10, cB11, cD0, cD1, cD2, cD3, cM00, cM01, cM10, cM11)
  for (int i = 0; i < NTILE; i += 2) {
    const int t1 = (i + 1 < NTILE) ? i + 1 : i;
    LOADT(t1, nB00, nB01, nB10, nB11, nD0, nD1, nD2, nD3, nM00, nM01, nM10, nM11)
    COMPT(cB00, cB01, cB10, cB11, cD0, cD1, cD2, cD3, cM00, cM01, cM10, cM11)
    const int t2 = (i + 2 < NTILE) ? i + 2 : i;
    LOADT(t2, cB00, cB01, cB10, cB11, cD0, cD1, cD2, cD3, cM00, cM01, cM10, cM11)
    COMPT(nB00, nB01, nB10, nB11, nD0, nD1, nD2, nD3, nM00, nM01, nM10, nM11)
  }
  #undef LOADT
  #undef COMPT

  // row-sums: lane (q,m) covered cols {T*64 + k*32 + q*8+e} — union over q
  // (and k,T,e) is the full 2048-col slice. Reduce over q (xor 16, 32).
  // All 4 waves hold identical sums (A duplicated); wave 0 writes both rows.
  ls0 += __shfl_xor(ls0, 16);
  ls0 += __shfl_xor(ls0, 32);
  ls1 += __shfl_xor(ls1, 16);
  ls1 += __shfl_xor(ls1, 32);
  if (w == 0 && q == 0) {
    lp[(size_t)jp * N + R0 + m] = ls0;
    lp[(size_t)jp * N + R0 + 16 + m] = ls1;
  }

  // partial store (C/D layout: row = q*4+ri, col = m within 16-tile)
  float* Pp = P + ((size_t)jp * N + R0) * FOUT;
  #pragma unroll
  for (int rh = 0; rh < 2; ++rh)
    #pragma unroll
    for (int n = 0; n < 2; ++n)
      #pragma unroll
      for (int ri = 0; ri < 4; ++ri)
        Pp[(size_t)(rh * 16 + q * 4 + ri) * FOUT + (nt0 + n) * 16 + m] =
            acc[rh][n][ri];
}

// ---------------------------------------------------------------------------
// Kernel 3: sum JP partials, normalize by row-sum. ~36 MB traffic.
// ---------------------------------------------------------------------------
__global__ __launch_bounds__(256) void k_norm(const float* __restrict__ P,
                                              const float* __restrict__ lp,
                                              float* __restrict__ out) {
  const int idx = blockIdx.x * 256 + threadIdx.x;   // 0 .. N*FOUT/4-1
  const int rr = idx >> 5;
  const int c4 = (idx & 31) * 4;
  float l = 0.f;
  #pragma unroll
  for (int j = 0; j < JP; ++j) l += lp[j * N + rr];
  const float inv = 1.0f / l;
  float4 s = {0.f, 0.f, 0.f, 0.f};
  #pragma unroll
  for (int j = 0; j < JP; ++j) {
    const float4 p = *(const float4*)(P + ((size_t)j * N + rr) * FOUT + c4);
    s.x += p.x; s.y += p.y; s.z += p.z; s.w += p.w;
  }
  s.x *= inv; s.y *= inv; s.z *= inv; s.w *= inv;
  *(float4*)(out + (size_t)rr * FOUT + c4) = s;
}

extern "C" void kernel_launch(void* const* d_in, const int* in_sizes, int n_in,
                              void* d_out, int out_size, void* d_ws, size_t ws_size,
                              hipStream_t stream) {
  const float* x   = (const float*)d_in[0];
  const int*   adj = (const int*)d_in[1];
  const float* W   = (const float*)d_in[2];
  const float* a   = (const float*)d_in[3];
  float* out = (float*)d_out;

  char* ws = (char*)d_ws;
  u16*   hT3  = (u16*)ws;     ws += (size_t)FOUT * N * sizeof(u16);            // 2 MB
  float* srcv = (float*)ws;   ws += (size_t)N * sizeof(float);
  float* dstv = (float*)ws;   ws += (size_t)N * sizeof(float);
  float* P    = (float*)ws;   ws += (size_t)JP * N * FOUT * sizeof(float);     // 16 MB
  float* lp   = (float*)ws;   ws += (size_t)JP * N * sizeof(float);
  u8*    bmk  = (u8*)ws;      ws += (size_t)N * (N / 8);                       // 8 MB

  k_pack<<<(N / 32) * (N / 256), 256, 0, stream>>>(adj, (uint32_t*)bmk);
  k_proj<<<N / 8, 256, 0, stream>>>(x, W, a, hT3, srcv, dstv);
  k_gat <<<256 * JP, 256, 0, stream>>>(bmk, hT3, srcv, dstv, P, lp);
  k_norm<<<(N * FOUT / 4) / 256, 256, 0, stream>>>(P, lp, out);
}

// Round 5
// 477.481 us; speedup vs baseline: 1.0506x; 1.0506x over previous
//
#include <hip/hip_runtime.h>
#include <cstdint>

#define N 8192
#define FIN 256
#define FOUT 128
#define ALPHA 0.2f
#define JP 4                  // j-split
#define JSL (N / JP)          // 2048 j per block
#define TJ 64                 // j-tile
#define NTILE (JSL / TJ)      // 32 tiles
#define RB 32                 // rows per block
#define SST 72                // S stride in u16 (16B-aligned rows, baseline banks)

typedef unsigned short u16;
typedef unsigned char u8;
typedef __attribute__((ext_vector_type(8))) short short8;
typedef __attribute__((ext_vector_type(4))) float floatx4;

__device__ __forceinline__ u16 bf16_rne(float f) {
  uint32_t u = __float_as_uint(f);
  u += 0x7fff + ((u >> 16) & 1);
  return (u16)(u >> 16);
}

// async global->LDS DMA, 16 B per lane, whole wave. LDS dest = uniform base
// + lane*16 (m104: wave-uniform base, lane-contiguous — layout must match).
__device__ __forceinline__ void gl_lds16(const void* g, void* l) {
  __builtin_amdgcn_global_load_lds(
      (const __attribute__((address_space(1))) void*)g,
      (__attribute__((address_space(3))) void*)l, 16, 0, 0);
}

// ---------------------------------------------------------------------------
// Kernel 0: adj (int32, 268 MB) -> bitmask (8 MB). Pure streaming at full
// HBM BW (~44 us, irreducible: adj must be read once).
// ---------------------------------------------------------------------------
__global__ __launch_bounds__(256) void k_pack(const int* __restrict__ adj,
                                              uint32_t* __restrict__ bm) {
  const int t = blockIdx.x * 256 + threadIdx.x;    // 0 .. N*N/32-1
  const int4* p = (const int4*)adj + (size_t)t * 8;
  int4 v[8];
  #pragma unroll
  for (int k = 0; k < 8; ++k) v[k] = p[k];
  uint32_t m = 0;
  #pragma unroll
  for (int k = 0; k < 8; ++k) {
    m |= (uint32_t)(v[k].x > 0) << (4 * k + 0);
    m |= (uint32_t)(v[k].y > 0) << (4 * k + 1);
    m |= (uint32_t)(v[k].z > 0) << (4 * k + 2);
    m |= (uint32_t)(v[k].w > 0) << (4 * k + 3);
  }
  bm[t] = m;
}

// ---------------------------------------------------------------------------
// Kernel 1: h = x@W (fp32); hT3 bf16 tiled [jb][nt][m*4+q][8]; src = h@a1,
// dst = h@a2.  (round-2 version, unchanged)
// ---------------------------------------------------------------------------
__global__ __launch_bounds__(256) void k_proj(const float* __restrict__ x,
                                              const float* __restrict__ W,
                                              const float* __restrict__ a,
                                              u16* __restrict__ hT3,
                                              float* __restrict__ srcv,
                                              float* __restrict__ dstv) {
  __shared__ float xs[8 * FIN];                     // 8 KB
  __shared__ float partS[4][4], partD[4][4];
  const int t = threadIdx.x;
  const int R0 = blockIdx.x * 8;

  const float4* xv = (const float4*)(x + (size_t)R0 * FIN);
  float4* xsv = (float4*)xs;
  xsv[t] = xv[t];
  xsv[t + 256] = xv[t + 256];
  __syncthreads();

  const int c  = t & 127;
  const int rg = (t >> 7) * 4;

  float acc[4] = {0.f, 0.f, 0.f, 0.f};
  float wa[4], wb[4];
  #pragma unroll
  for (int j = 0; j < 4; ++j) wa[j] = W[j * FOUT + c];
  #pragma unroll
  for (int j = 0; j < 4; ++j) wb[j] = W[(4 + j) * FOUT + c];

  for (int k4 = 0; k4 < FIN / 4; ++k4) {
    float wc[4];
    #pragma unroll
    for (int j = 0; j < 4; ++j) { wc[j] = wa[j]; wa[j] = wb[j]; }
    const int kn = (k4 + 2 < FIN / 4) ? k4 + 2 : k4;
    #pragma unroll
    for (int j = 0; j < 4; ++j) wb[j] = W[(kn * 4 + j) * FOUT + c];
    #pragma unroll
    for (int i = 0; i < 4; ++i) {
      const float4 xq = *(const float4*)&xs[(rg + i) * FIN + k4 * 4];
      acc[i] += xq.x * wc[0] + xq.y * wc[1] + xq.z * wc[2] + xq.w * wc[3];
    }
  }

  {
    const int j = R0 + rg;
    const int jb = j >> 5, q = (j >> 3) & 3, jj = j & 7;
    const int m = c & 15, nt = c >> 4;
    union { u16 u[4]; uint2 v; } pk;
    #pragma unroll
    for (int i = 0; i < 4; ++i) pk.u[i] = bf16_rne(acc[i]);
    *(uint2*)(hT3 + (size_t)(((jb * 8 + nt) * 64) + (m * 4 + q)) * 8 + jj) = pk.v;
  }

  const float a1 = a[c], a2 = a[FOUT + c];
  float s4[4], d4[4];
  #pragma unroll
  for (int i = 0; i < 4; ++i) { s4[i] = acc[i] * a1; d4[i] = acc[i] * a2; }
  #pragma unroll
  for (int off = 32; off > 0; off >>= 1) {
    #pragma unroll
    for (int i = 0; i < 4; ++i) {
      s4[i] += __shfl_down(s4[i], off);
      d4[i] += __shfl_down(d4[i], off);
    }
  }
  const int wv = t >> 6, lane = t & 63;
  if (lane == 0) {
    #pragma unroll
    for (int i = 0; i < 4; ++i) { partS[wv][i] = s4[i]; partD[wv][i] = d4[i]; }
  }
  __syncthreads();
  if (t < 16) {
    const int i = t & 3, rg2 = (t >> 2) & 1, which = t >> 3;
    if (which == 0) srcv[R0 + rg2 * 4 + i] = partS[rg2*2][i] + partS[rg2*2+1][i];
    else            dstv[R0 + rg2 * 4 + i] = partD[rg2*2][i] + partD[rg2*2+1][i];
  }
}

// ---------------------------------------------------------------------------
// Kernel 2: fused GAT — EXACT round-2 version (best known: barrier-phased,
// DMA-staged hS, S-tile in LDS, counted-vmcnt barriers). This round it is
// LAUNCHED TWICE (idempotent: pure stores to P/lp from read-only inputs) as
// a direct duration probe: dur_us(this round) - dur_us(r2) = one k_gat.
// ---------------------------------------------------------------------------
__global__ __launch_bounds__(256, 4) void k_gat(const u8* __restrict__ bmk,
                                                const u16* __restrict__ hT3,
                                                const float* __restrict__ srcv,
                                                const float* __restrict__ dstv,
                                                float* __restrict__ P,
                                                float* __restrict__ lp) {
  __shared__ u16 hS[2][8192];      // 2 x 16 KB staged hT tiles
  __shared__ u16 S[RB * SST];      // 4.6 KB p-tile (bf16)
  const int t = threadIdx.x;
  const int wv = t >> 6, lane = t & 63;
  const int q = lane >> 4, m = lane & 15;
  const int bm = blockIdx.x & 255;
  const int jp = blockIdx.x >> 8;
  const int R0 = bm * RB;
  const int j0 = jp * JSL;

  // p-phase mapping: thread -> (row pr, 8 cols at pc)
  const int pr = t >> 3;
  const int pc = (t & 7) * 8;
  const float srcr = srcv[R0 + pr];
  // bitmask byte for (row R0+pr, cols j0+pc .. +7); per tile advance = 8 B
  const u8*    bmp  = bmk + (size_t)(R0 + pr) * (N / 8) + (j0 + pc) / 8;
  const float* dstp = dstv + j0 + pc;

  // MFMA mapping: wave -> (row-half rh, col-half ch)
  const int rh = wv & 1, ch = wv >> 1;
  const int Lq = m * 4 + q;                      // hT3/hS lane index

  floatx4 acc[4];
  #pragma unroll
  for (int nt = 0; nt < 4; ++nt) acc[nt] = (floatx4){0.f, 0.f, 0.f, 0.f};
  float lsum = 0.f;

  // DMA one tile (16 KB = 16 chunks of 1 KB); wave wv stages chunks wv*4..+4
  const size_t jb00 = (size_t)(j0 >> 5);         // first global jb of slice
  #define STAGE(I, BUF)                                                        \
  {                                                                            \
    _Pragma("unroll")                                                          \
    for (int cc = 0; cc < 4; ++cc) {                                           \
      const int kc = wv * 4 + cc;               /* 0..15 */                    \
      const int jbl = kc >> 3, nt_ = kc & 7;                                   \
      const u16* src = hT3 + ((jb00 + (size_t)(I) * 2 + jbl) * 8 + nt_) * 512  \
                       + (size_t)lane * 8;                                     \
      gl_lds16(src, &hS[BUF][kc * 512]);                                       \
    }                                                                          \
  }

  // prologue: stage tile 0 into buf 0; register-prefetch tile 0 mask/dst
  STAGE(0, 0)
  __builtin_amdgcn_sched_barrier(0);   // DMAs strictly oldest in VMEM queue
  u8     aC  = bmp[0];
  float4 dC0 = *(const float4*)(dstp),   dC1 = *(const float4*)(dstp + 4);

  int buf = 0;
  for (int i = 0; i < NTILE; ++i) {
    // B1: retire this tile's 4 DMA chunks (oldest); keep the 3 mask/dst
    // prefetch loads in flight. lgkmcnt(0): all waves' prior LDS reads done
    // before S / hS[buf^1] get overwritten after the barrier.
    asm volatile("s_waitcnt vmcnt(3) lgkmcnt(0)" ::: "memory");
    __builtin_amdgcn_s_barrier();
    __builtin_amdgcn_sched_barrier(0);

    // DMA tile i+1 into the other buffer; reg-prefetch mask/dst for tile i+1
    const int nx = (i + 1 < NTILE) ? i + 1 : i;
    if (i + 1 < NTILE) STAGE(i + 1, buf ^ 1)
    __builtin_amdgcn_sched_barrier(0);   // pin: 4 DMA issued before reg loads
    u8     aN  = bmp[nx * 8];
    float4 dN0 = *(const float4*)(dstp + nx * TJ);
    float4 dN1 = *(const float4*)(dstp + nx * TJ + 4);

    // p-phase: 8 p-values/thread from prefetched regs -> S (bf16)
    {
      const float df[8] = {dC0.x, dC0.y, dC0.z, dC0.w, dC1.x, dC1.y, dC1.z, dC1.w};
      union { u16 u[8]; short8 s; } pk;
      #pragma unroll
      for (int e = 0; e < 8; ++e) {
        float v = srcr + df[e];
        v = fmaxf(v, ALPHA * v);
        const float p = ((aC >> e) & 1) ? __expf(v) : 0.f;
        lsum += p;
        pk.u[e] = bf16_rne(p);
      }
      *(short8*)&S[pr * SST + pc] = pk.s;
    }

    // B2: LDS-only barrier — S ds_writes visible to all waves; the DMA for
    // tile i+1 and the mask/dst loads remain in flight (no vmcnt drain).
    asm volatile("s_waitcnt lgkmcnt(0)" ::: "memory");
    __builtin_amdgcn_s_barrier();
    __builtin_amdgcn_sched_barrier(0);

    // MFMA: A-frags from S, B-frags from hS[buf]
    {
      const short8 a0 = *(const short8*)&S[(rh * 16 + m) * SST + q * 8];
      const short8 a1 = *(const short8*)&S[(rh * 16 + m) * SST + 32 + q * 8];
      #pragma unroll
      for (int nt = 0; nt < 4; ++nt) {
        const short8 b0 = *(const short8*)&hS[buf][(0 * 8 + ch * 4 + nt) * 512 + Lq * 8];
        const short8 b1 = *(const short8*)&hS[buf][(1 * 8 + ch * 4 + nt) * 512 + Lq * 8];
        acc[nt] = __builtin_amdgcn_mfma_f32_16x16x32_bf16(a0, b0, acc[nt], 0, 0, 0);
        acc[nt] = __builtin_amdgcn_mfma_f32_16x16x32_bf16(a1, b1, acc[nt], 0, 0, 0);
      }
    }

    aC = aN; dC0 = dN0; dC1 = dN1;
    buf ^= 1;
  }
  #undef STAGE

  // row-sum: reduce over the 8 threads sharing row pr (aligned groups)
  lsum += __shfl_down(lsum, 4);
  lsum += __shfl_down(lsum, 2);
  lsum += __shfl_down(lsum, 1);
  if ((t & 7) == 0) lp[(size_t)jp * N + R0 + pr] = lsum;

  // partial store (C/D layout: row = q*4+ri, col = nt*16+m)
  float* Pp = P + ((size_t)jp * N + R0 + rh * 16) * FOUT + ch * 64;
  #pragma unroll
  for (int nt = 0; nt < 4; ++nt)
    #pragma unroll
    for (int ri = 0; ri < 4; ++ri)
      Pp[(size_t)(q * 4 + ri) * FOUT + nt * 16 + m] = acc[nt][ri];
}

// ---------------------------------------------------------------------------
// Kernel 3: sum JP partials, normalize by row-sum. ~36 MB traffic.
// ---------------------------------------------------------------------------
__global__ __launch_bounds__(256) void k_norm(const float* __restrict__ P,
                                              const float* __restrict__ lp,
                                              float* __restrict__ out) {
  const int idx = blockIdx.x * 256 + threadIdx.x;   // 0 .. N*FOUT/4-1
  const int rr = idx >> 5;
  const int c4 = (idx & 31) * 4;
  float l = 0.f;
  #pragma unroll
  for (int j = 0; j < JP; ++j) l += lp[j * N + rr];
  const float inv = 1.0f / l;
  float4 s = {0.f, 0.f, 0.f, 0.f};
  #pragma unroll
  for (int j = 0; j < JP; ++j) {
    const float4 p = *(const float4*)(P + ((size_t)j * N + rr) * FOUT + c4);
    s.x += p.x; s.y += p.y; s.z += p.z; s.w += p.w;
  }
  s.x *= inv; s.y *= inv; s.z *= inv; s.w *= inv;
  *(float4*)(out + (size_t)rr * FOUT + c4) = s;
}

extern "C" void kernel_launch(void* const* d_in, const int* in_sizes, int n_in,
                              void* d_out, int out_size, void* d_ws, size_t ws_size,
                              hipStream_t stream) {
  const float* x   = (const float*)d_in[0];
  const int*   adj = (const int*)d_in[1];
  const float* W   = (const float*)d_in[2];
  const float* a   = (const float*)d_in[3];
  float* out = (float*)d_out;

  char* ws = (char*)d_ws;
  u16*   hT3  = (u16*)ws;     ws += (size_t)FOUT * N * sizeof(u16);            // 2 MB
  float* srcv = (float*)ws;   ws += (size_t)N * sizeof(float);
  float* dstv = (float*)ws;   ws += (size_t)N * sizeof(float);
  float* P    = (float*)ws;   ws += (size_t)JP * N * FOUT * sizeof(float);     // 16 MB
  float* lp   = (float*)ws;   ws += (size_t)JP * N * sizeof(float);
  u8*    bmk  = (u8*)ws;      ws += (size_t)N * (N / 8);                       // 8 MB

  k_pack<<<(N / 32) * (N / 256), 256, 0, stream>>>(adj, (uint32_t*)bmk);
  k_proj<<<N / 8, 256, 0, stream>>>(x, W, a, hT3, srcv, dstv);
  // PROBE: k_gat launched twice (idempotent). dur_us - dur_us(r2) = one
  // k_gat duration — direct attribution the truncated top-5 can't give.
  k_gat <<<256 * JP, 256, 0, stream>>>(bmk, hT3, srcv, dstv, P, lp);
  k_gat <<<256 * JP, 256, 0, stream>>>(bmk, hT3, srcv, dstv, P, lp);
  k_norm<<<(N * FOUT / 4) / 256, 256, 0, stream>>>(P, lp, out);
}

// Round 6
// 429.523 us; speedup vs baseline: 1.1679x; 1.1117x over previous
//
#include <hip/hip_runtime.h>
#include <cstdint>

#define N 8192
#define FIN 256
#define FOUT 128
#define ALPHA 0.2f
#define JP 2                  // j-split (512 gat blocks, 2/CU co-resident)
#define JSL (N / JP)          // 4096 j per block
#define TJ 64                 // j-tile
#define NTILE (JSL / TJ)      // 64 tiles
#define RB 32                 // rows per block
#define SST 72                // S stride in u16 (16B-aligned rows, baseline banks)

typedef unsigned short u16;
typedef unsigned char u8;
typedef __attribute__((ext_vector_type(8))) short short8;
typedef __attribute__((ext_vector_type(4))) float floatx4;

__device__ __forceinline__ u16 bf16_rne(float f) {
  uint32_t u = __float_as_uint(f);
  u += 0x7fff + ((u >> 16) & 1);
  return (u16)(u >> 16);
}

// async global->LDS DMA, 16 B per lane, whole wave. LDS dest = uniform base
// + lane*16 (m104); global src IS per-lane (m173).
__device__ __forceinline__ void gl_lds16(const void* g, void* l) {
  __builtin_amdgcn_global_load_lds(
      (const __attribute__((address_space(1))) void*)g,
      (__attribute__((address_space(3))) void*)l, 16, 0, 0);
}

// ---------------------------------------------------------------------------
// Kernel 1: h = x@W (fp32); hT3 bf16 tiled [jb][nt][m*4+q][8]; src = h@a1,
// dst = h@a2.  (round-2 version, unchanged)
// ---------------------------------------------------------------------------
__global__ __launch_bounds__(256) void k_proj(const float* __restrict__ x,
                                              const float* __restrict__ W,
                                              const float* __restrict__ a,
                                              u16* __restrict__ hT3,
                                              float* __restrict__ srcv,
                                              float* __restrict__ dstv) {
  __shared__ float xs[8 * FIN];                     // 8 KB
  __shared__ float partS[4][4], partD[4][4];
  const int t = threadIdx.x;
  const int R0 = blockIdx.x * 8;

  const float4* xv = (const float4*)(x + (size_t)R0 * FIN);
  float4* xsv = (float4*)xs;
  xsv[t] = xv[t];
  xsv[t + 256] = xv[t + 256];
  __syncthreads();

  const int c  = t & 127;
  const int rg = (t >> 7) * 4;

  float acc[4] = {0.f, 0.f, 0.f, 0.f};
  float wa[4], wb[4];
  #pragma unroll
  for (int j = 0; j < 4; ++j) wa[j] = W[j * FOUT + c];
  #pragma unroll
  for (int j = 0; j < 4; ++j) wb[j] = W[(4 + j) * FOUT + c];

  for (int k4 = 0; k4 < FIN / 4; ++k4) {
    float wc[4];
    #pragma unroll
    for (int j = 0; j < 4; ++j) { wc[j] = wa[j]; wa[j] = wb[j]; }
    const int kn = (k4 + 2 < FIN / 4) ? k4 + 2 : k4;
    #pragma unroll
    for (int j = 0; j < 4; ++j) wb[j] = W[(kn * 4 + j) * FOUT + c];
    #pragma unroll
    for (int i = 0; i < 4; ++i) {
      const float4 xq = *(const float4*)&xs[(rg + i) * FIN + k4 * 4];
      acc[i] += xq.x * wc[0] + xq.y * wc[1] + xq.z * wc[2] + xq.w * wc[3];
    }
  }

  {
    const int j = R0 + rg;
    const int jb = j >> 5, q = (j >> 3) & 3, jj = j & 7;
    const int m = c & 15, nt = c >> 4;
    union { u16 u[4]; uint2 v; } pk;
    #pragma unroll
    for (int i = 0; i < 4; ++i) pk.u[i] = bf16_rne(acc[i]);
    *(uint2*)(hT3 + (size_t)(((jb * 8 + nt) * 64) + (m * 4 + q)) * 8 + jj) = pk.v;
  }

  const float a1 = a[c], a2 = a[FOUT + c];
  float s4[4], d4[4];
  #pragma unroll
  for (int i = 0; i < 4; ++i) { s4[i] = acc[i] * a1; d4[i] = acc[i] * a2; }
  #pragma unroll
  for (int off = 32; off > 0; off >>= 1) {
    #pragma unroll
    for (int i = 0; i < 4; ++i) {
      s4[i] += __shfl_down(s4[i], off);
      d4[i] += __shfl_down(d4[i], off);
    }
  }
  const int wv = t >> 6, lane = t & 63;
  if (lane == 0) {
    #pragma unroll
    for (int i = 0; i < 4; ++i) { partS[wv][i] = s4[i]; partD[wv][i] = d4[i]; }
  }
  __syncthreads();
  if (t < 16) {
    const int i = t & 3, rg2 = (t >> 2) & 1, which = t >> 3;
    if (which == 0) srcv[R0 + rg2 * 4 + i] = partS[rg2*2][i] + partS[rg2*2+1][i];
    else            dstv[R0 + rg2 * 4 + i] = partD[rg2*2][i] + partD[rg2*2+1][i];
  }
}

// ---------------------------------------------------------------------------
// Kernel 2: fused GAT — r2 skeleton + adj staged via DMA (k_pack DELETED).
// Round-5 probe pinned k_gat(r2) = 42 us and k_pack = 44 us; adj's 268 MB
// HBM stream moves INTO the DMA queue here (per tile: 8 KB adj alongside
// 16 KB hT), decoupled from all register deps — the failure mode of r1's
// reg-prefetched adj. p-phase reads the mask from adjS (2x ds_read_b128).
// Per iter per wave: 6 DMA + 2 dst loads -> B1 = vmcnt(2) (retires exactly
// the 6 DMAs, oldest by sched_barrier pinning); B2 = lgkmcnt(0) only.
// JP=2: 512 blocks, 2/CU (LDS 52.6 KB/block), all co-resident.
// ---------------------------------------------------------------------------
__global__ __launch_bounds__(256, 2) void k_gat(const int* __restrict__ adj,
                                                const u16* __restrict__ hT3,
                                                const float* __restrict__ srcv,
                                                const float* __restrict__ dstv,
                                                float* __restrict__ P,
                                                float* __restrict__ lp) {
  __shared__ u16 hS[2][8192];      // 2 x 16 KB staged hT tiles
  __shared__ int adjS[2][2048];    // 2 x 8 KB staged adj tiles (32 x 64 int)
  __shared__ u16 S[RB * SST];      // 4.6 KB p-tile (bf16)
  const int t = threadIdx.x;
  const int wv = t >> 6, lane = t & 63;
  const int q = lane >> 4, m = lane & 15;
  const int bm = blockIdx.x & 255;
  const int jp = blockIdx.x >> 8;
  const int R0 = bm * RB;
  const int j0 = jp * JSL;

  // p-phase mapping: thread -> (row pr, 8 cols at pc)
  const int pr = t >> 3;
  const int pc = (t & 7) * 8;
  const float srcr = srcv[R0 + pr];
  const float* dstp = dstv + j0 + pc;

  // MFMA mapping: wave -> (row-half rh, col-half ch)
  const int rh = wv & 1, ch = wv >> 1;
  const int Lq = m * 4 + q;                      // hT3/hS lane index

  floatx4 acc[4];
  #pragma unroll
  for (int nt = 0; nt < 4; ++nt) acc[nt] = (floatx4){0.f, 0.f, 0.f, 0.f};
  float lsum = 0.f;

  // DMA one tile: hT 16 KB (16 chunks, wave wv: 4) + adj 8 KB (8 chunks,
  // wave wv: 2). adj chunk c (1 KB): rows c*4+(lane>>4), cols (lane&15)*4
  // -> LDS adjS row-major [32][64] (row = 256 B, lane-linear ✓).
  const size_t jb00 = (size_t)(j0 >> 5);         // first global jb of slice
  #define STAGE(I, BUF)                                                        \
  {                                                                            \
    _Pragma("unroll")                                                          \
    for (int cc = 0; cc < 4; ++cc) {                                           \
      const int kc = wv * 4 + cc;               /* 0..15 */                    \
      const int jbl = kc >> 3, nt_ = kc & 7;                                   \
      const u16* src = hT3 + ((jb00 + (size_t)(I) * 2 + jbl) * 8 + nt_) * 512  \
                       + (size_t)lane * 8;                                     \
      gl_lds16(src, &hS[BUF][kc * 512]);                                       \
    }                                                                          \
    _Pragma("unroll")                                                          \
    for (int cc = 0; cc < 2; ++cc) {                                           \
      const int c_ = wv * 2 + cc;               /* 0..7 */                     \
      const int* asrc = adj + (size_t)(R0 + c_ * 4 + (lane >> 4)) * N          \
                        + j0 + (I) * TJ + (lane & 15) * 4;                     \
      gl_lds16(asrc, &adjS[BUF][c_ * 256]);                                    \
    }                                                                          \
  }

  // prologue: stage tile 0 into buf 0; register-prefetch tile-0 dst
  STAGE(0, 0)
  __builtin_amdgcn_sched_barrier(0);   // DMAs strictly oldest in VMEM queue
  float4 dC0 = *(const float4*)(dstp),   dC1 = *(const float4*)(dstp + 4);

  int buf = 0;
  for (int i = 0; i < NTILE; ++i) {
    // B1: retire this tile's 6 DMA chunks (oldest); keep the 2 dst prefetch
    // loads in flight. lgkmcnt(0): all waves' prior LDS reads done before
    // S / hS[buf^1] / adjS[buf^1] get overwritten after the barrier.
    asm volatile("s_waitcnt vmcnt(2) lgkmcnt(0)" ::: "memory");
    __builtin_amdgcn_s_barrier();
    __builtin_amdgcn_sched_barrier(0);

    // mask for tile i from adjS[buf] (DMA'd last iter, retired at B1);
    // issue the ds_reads before STAGE so their latency hides under it
    const int4 A0 = *((const int4*)adjS[buf] + pr * 16 + (t & 7) * 2);
    const int4 A1 = *((const int4*)adjS[buf] + pr * 16 + (t & 7) * 2 + 1);

    // DMA tile i+1 into the other buffer; reg-prefetch dst for tile i+1
    const int nx = (i + 1 < NTILE) ? i + 1 : i;
    if (i + 1 < NTILE) STAGE(i + 1, buf ^ 1)
    __builtin_amdgcn_sched_barrier(0);   // pin: 6 DMA issued before dst loads
    float4 dN0 = *(const float4*)(dstp + nx * TJ);
    float4 dN1 = *(const float4*)(dstp + nx * TJ + 4);

    // p-phase: 8 p-values/thread (mask from LDS, dst from regs) -> S (bf16)
    {
      const int   ai[8] = {A0.x, A0.y, A0.z, A0.w, A1.x, A1.y, A1.z, A1.w};
      const float df[8] = {dC0.x, dC0.y, dC0.z, dC0.w, dC1.x, dC1.y, dC1.z, dC1.w};
      union { u16 u[8]; short8 s; } pk;
      #pragma unroll
      for (int e = 0; e < 8; ++e) {
        float v = srcr + df[e];
        v = fmaxf(v, ALPHA * v);
        const float p = ai[e] > 0 ? __expf(v) : 0.f;
        lsum += p;
        pk.u[e] = bf16_rne(p);
      }
      *(short8*)&S[pr * SST + pc] = pk.s;
    }

    // B2: LDS-only barrier — S ds_writes visible; DMA for tile i+1 and dst
    // loads remain in flight (no vmcnt drain).
    asm volatile("s_waitcnt lgkmcnt(0)" ::: "memory");
    __builtin_amdgcn_s_barrier();
    __builtin_amdgcn_sched_barrier(0);

    // MFMA: A-frags from S, B-frags from hS[buf]
    {
      const short8 a0 = *(const short8*)&S[(rh * 16 + m) * SST + q * 8];
      const short8 a1 = *(const short8*)&S[(rh * 16 + m) * SST + 32 + q * 8];
      #pragma unroll
      for (int nt = 0; nt < 4; ++nt) {
        const short8 b0 = *(const short8*)&hS[buf][(0 * 8 + ch * 4 + nt) * 512 + Lq * 8];
        const short8 b1 = *(const short8*)&hS[buf][(1 * 8 + ch * 4 + nt) * 512 + Lq * 8];
        acc[nt] = __builtin_amdgcn_mfma_f32_16x16x32_bf16(a0, b0, acc[nt], 0, 0, 0);
        acc[nt] = __builtin_amdgcn_mfma_f32_16x16x32_bf16(a1, b1, acc[nt], 0, 0, 0);
      }
    }

    dC0 = dN0; dC1 = dN1;
    buf ^= 1;
  }
  #undef STAGE

  // row-sum: reduce over the 8 threads sharing row pr (aligned groups)
  lsum += __shfl_down(lsum, 4);
  lsum += __shfl_down(lsum, 2);
  lsum += __shfl_down(lsum, 1);
  if ((t & 7) == 0) lp[(size_t)jp * N + R0 + pr] = lsum;

  // partial store (C/D layout: row = q*4+ri, col = nt*16+m)
  float* Pp = P + ((size_t)jp * N + R0 + rh * 16) * FOUT + ch * 64;
  #pragma unroll
  for (int nt = 0; nt < 4; ++nt)
    #pragma unroll
    for (int ri = 0; ri < 4; ++ri)
      Pp[(size_t)(q * 4 + ri) * FOUT + nt * 16 + m] = acc[nt][ri];
}

// ---------------------------------------------------------------------------
// Kernel 3: sum JP partials, normalize by row-sum. ~20 MB traffic at JP=2.
// ---------------------------------------------------------------------------
__global__ __launch_bounds__(256) void k_norm(const float* __restrict__ P,
                                              const float* __restrict__ lp,
                                              float* __restrict__ out) {
  const int idx = blockIdx.x * 256 + threadIdx.x;   // 0 .. N*FOUT/4-1
  const int rr = idx >> 5;
  const int c4 = (idx & 31) * 4;
  float l = 0.f;
  #pragma unroll
  for (int j = 0; j < JP; ++j) l += lp[j * N + rr];
  const float inv = 1.0f / l;
  float4 s = {0.f, 0.f, 0.f, 0.f};
  #pragma unroll
  for (int j = 0; j < JP; ++j) {
    const float4 p = *(const float4*)(P + ((size_t)j * N + rr) * FOUT + c4);
    s.x += p.x; s.y += p.y; s.z += p.z; s.w += p.w;
  }
  s.x *= inv; s.y *= inv; s.z *= inv; s.w *= inv;
  *(float4*)(out + (size_t)rr * FOUT + c4) = s;
}

extern "C" void kernel_launch(void* const* d_in, const int* in_sizes, int n_in,
                              void* d_out, int out_size, void* d_ws, size_t ws_size,
                              hipStream_t stream) {
  const float* x   = (const float*)d_in[0];
  const int*   adj = (const int*)d_in[1];
  const float* W   = (const float*)d_in[2];
  const float* a   = (const float*)d_in[3];
  float* out = (float*)d_out;

  char* ws = (char*)d_ws;
  u16*   hT3  = (u16*)ws;     ws += (size_t)FOUT * N * sizeof(u16);            // 2 MB
  float* srcv = (float*)ws;   ws += (size_t)N * sizeof(float);
  float* dstv = (float*)ws;   ws += (size_t)N * sizeof(float);
  float* P    = (float*)ws;   ws += (size_t)JP * N * FOUT * sizeof(float);     // 8 MB
  float* lp   = (float*)ws;   ws += (size_t)JP * N * sizeof(float);

  k_proj<<<N / 8, 256, 0, stream>>>(x, W, a, hT3, srcv, dstv);
  k_gat <<<256 * JP, 256, 0, stream>>>(adj, hT3, srcv, dstv, P, lp);
  k_norm<<<(N * FOUT / 4) / 256, 256, 0, stream>>>(P, lp, out);
}